// Round 1
// baseline (73.190 us; speedup 1.0000x reference)
//
#include <hip/hip_runtime.h>

#define GH 52
#define GW 52
#define NB 5
#define NCELL (GH*GW)        // 2704
#define NBOX (NCELL*NB)      // 13520
#define SCALE 8.0f           // 416/52
#define NORMY 416.0f
#define IOU_T 0.4f

#define TS 4                 // interior tile (cells); 52 % 4 == 0 -> no partial tiles
#define HS (TS+2)            // halo tile 6x6
#define TBOX (HS*HS*NB)      // 180 boxes staged in LDS
#define NTX (GW/TS)          // 13
#define NTY (GH/TS)          // 13

// ---- nms kernel geometry: strip-owned, aligned-window act grid ----
#define PW2 56               // padded row stride (bytes): 1+52+1 halo, rounded to 56
                             // -> every strip window (row*56 + 4*s) is 4B-aligned
#define PR  54               // padded rows (1+52+1)
#define PC2 (PR*PW2)         // 3024 bytes
#define NSTRIP 13            // 4-cell strips per row
#define NTHR (GH*NSTRIP)     // 676 worker threads
#define BLK 704              // 11 waves (>= NTHR, multiple of 64)

// ---- Kernel 1: fused decode + suppression-mask build (tile + halo in LDS) ----
// For box j, predecessors (higher priority: score desc, index asc; IoU>0.4) all
// lie in the 3x3 cell neighborhood -> 45 slots -> one u64 bitmask per box.
// Slot layout: bit (dy+1)*15 + (dx+1)*5 + nb2  (matches nms V-vector build).
// Masks stored plane-major: masks[b*NCELL + cell] for coalesced nms preload.
__global__ __launch_bounds__(192) void decode_adj_kernel(
        const float* __restrict__ x, float* __restrict__ out,
        unsigned long long* __restrict__ masks) {
    __shared__ float4 lbox[TBOX];
    __shared__ float  lsc[TBOX];
    int bx0 = (blockIdx.x % NTX) * TS;
    int by0 = (blockIdx.x / NTX) * TS;
    int t = threadIdx.x;

    // Stage 1: decode halo tile into LDS (one box/thread; invalid -> sentinel)
    if (t < TBOX) {
        int lcell = t / NB, b = t % NB;
        int lx = lcell % HS, ly = lcell / HS;
        int gx = bx0 + lx - 1, gy = by0 + ly - 1;
        float4 bb = make_float4(0.f, 0.f, 0.f, 0.f);
        float s = -1e30f;                       // sentinel: never a predecessor
        if (gx >= 0 && gx < GW && gy >= 0 && gy < GH) {
            const float* p = x + ((size_t)(gy * GW + gx) * NB + b) * 5;
            float c0 = p[0], c1 = p[1], c2 = p[2], c3 = p[3]; s = p[4];
            float cx = (c0 + (float)gx) * SCALE;
            float w  = c2 * SCALE;
            float cy = NORMY - (c1 + (float)gy) * SCALE;
            float h  = c3 * SCALE;
            bb = make_float4(cx - w * 0.5f, cy - h * 0.5f,
                             cx + w * 0.5f, cy + h * 0.5f);
        }
        lbox[t] = bb; lsc[t] = s;
    }
    __syncthreads();

    // Stage 2: interior boxes (one box/thread) -> out[0:5], 45-bit mask
    if (t < TS * TS * NB) {
        int lcell = t / NB, b = t % NB;
        int lxi = lcell % TS, lyi = lcell / TS;
        int gx = bx0 + lxi, gy = by0 + lyi;
        int lt = ((lyi + 1) * HS + (lxi + 1)) * NB + b;
        float4 bj = lbox[lt]; float sj = lsc[lt];
        int cell = gy * GW + gx;
        int j = cell * NB + b;
        float areaj = fmaxf(bj.z - bj.x, 0.f) * fmaxf(bj.w - bj.y, 0.f);
        unsigned long long m = 0ull;
        #pragma unroll
        for (int dy = -1; dy <= 1; ++dy)
        #pragma unroll
        for (int dx = -1; dx <= 1; ++dx)
        #pragma unroll
        for (int nb2 = 0; nb2 < NB; ++nb2) {
            int ln = ((lyi + 1 + dy) * HS + (lxi + 1 + dx)) * NB + nb2;
            int i = j + (dy * GW + dx) * NB + (nb2 - b);
            if (i == j) continue;
            float si = lsc[ln];
            // pri(i) > pri(j): score desc, stable-argsort index-asc tiebreak
            bool earlier = (si > sj) || (si == sj && i < j);
            if (!earlier) continue;
            float4 bi = lbox[ln];
            float iw = fmaxf(fminf(bi.z, bj.z) - fmaxf(bi.x, bj.x), 0.f);
            float ih = fmaxf(fminf(bi.w, bj.w) - fmaxf(bi.y, bj.y), 0.f);
            float inter = iw * ih;
            float areai = fmaxf(bi.z - bi.x, 0.f) * fmaxf(bi.w - bi.y, 0.f);
            float uni = areai + areaj - inter;
            float iou = (uni > 0.f) ? inter / fmaxf(uni, 1e-12f) : 0.f;
            if (iou > IOU_T)
                m |= 1ull << ((dy + 1) * 15 + (dx + 1) * 5 + nb2);
        }
        masks[b * NCELL + cell] = m;
        out[j * 5 + 0] = bj.x; out[j * 5 + 1] = bj.y;
        out[j * 5 + 2] = bj.z; out[j * 5 + 3] = bj.w;
        out[j * 5 + 4] = sj;
    }
}

// ---- Kernel 2: chaotic fixpoint active[j] = NOR(active[preds]) -------------
// Strip-owned: each worker thread owns 4 consecutive cells of one row
// (52 rows x 13 strips = 676 workers, 11 waves). A strip's 3x3 windows need 6
// consecutive act bytes per row; PW2=56 makes every window base 4B-aligned so
// each row is ONE ds_read_b32 + ONE ds_read_u16 (6 LDS reads/strip/pass vs 36
// byte-reads under the old cell-cyclic ownership). Row-dirty gating (exact) and
// 3-buffer flag rotation preserved; flags set by plain store (benign all-1 race)
// instead of atomicOr. Chaotic iteration converges to the unique DAG fixpoint
// (= exact greedy NMS): any stale in-pass read is re-flagged -> re-evaluated.
__global__ __launch_bounds__(BLK) void nms_kernel(
        const unsigned long long* __restrict__ masks,
        float* __restrict__ out) {
    __shared__ __align__(16) unsigned char act_s[PC2];
    __shared__ unsigned int rowflag[3][PR];
    int tid = threadIdx.x;
    bool wk = tid < NTHR;
    int row = tid / NSTRIP;          // 0..51 (garbage for idle threads, unused)
    int s   = tid - row * NSTRIP;    // 0..12
    int gx0 = s * 4;
    int cell0 = row * GW + gx0;

    // Masks for owned boxes -> registers (20 x u64); plane-major global layout,
    // L2-warm from kernel 1.
    unsigned long long cm[4][NB];
    #pragma unroll
    for (int c = 0; c < 4; ++c)
        #pragma unroll
        for (int b = 0; b < NB; ++b)
            cm[c][b] = wk ? masks[b * NCELL + cell0 + c] : 0ull;

    for (int i = tid; i < PC2; i += BLK) act_s[i] = 0;
    if (tid < PR) {
        rowflag[0][tid] = 0;                                   // cur  for pass 0
        rowflag[1][tid] = 0;                                   // next for pass 0
        rowflag[2][tid] = (tid >= 1 && tid <= GH) ? 1u : 0u;   // prev: all dirty
    }
    __syncthreads();
    for (int i = tid; i < NCELL; i += BLK) {
        int gy = i / GW, gxx = i - gy * GW;
        act_s[(gy + 1) * PW2 + gxx + 1] = 0x1F;
    }
    __syncthreads();

    // window base: rows row..row+2 (padded) starting at cell gx0-1 (padded gx0)
    int p0 = row * PW2 + gx0;            // 4B-aligned: 56*row + 4*s
    int pc = (row + 1) * PW2 + gx0 + 1;  // own cells' first byte

    int pprev = 2, pcur = 0, pnext = 1;
    for (int pass = 0; pass < 256; ++pass) {
        // clear next-pass buffer (not read/written this pass -> no barrier needed)
        if (tid < PR) rowflag[pnext][tid] = 0;
        const unsigned int* prevf = rowflag[pprev];
        bool mych = false;
        if (wk && (prevf[row] | prevf[row + 1] | prevf[row + 2]) != 0u) {
            unsigned r[3];
            #pragma unroll
            for (int k = 0; k < 3; ++k) {
                int p = p0 + k * PW2;
                unsigned lo = *(volatile unsigned int*)(act_s + p);
                unsigned hi = *(volatile unsigned short*)(act_s + p + 4);
                r[k] = (lo & 0x1F)
                     | (((lo >> 8)  & 0x1F) << 5)
                     | (((lo >> 16) & 0x1F) << 10)
                     | (((lo >> 24) & 0x1F) << 15)
                     | ((hi & 0x1F) << 20)
                     | (((hi >> 8) & 0x1F) << 25);
            }
            #pragma unroll
            for (int c = 0; c < 4; ++c) {
                unsigned long long V =
                      (unsigned long long)((r[0] >> (5 * c)) & 0x7FFF)
                    | ((unsigned long long)((r[1] >> (5 * c)) & 0x7FFF) << 15)
                    | ((unsigned long long)((r[2] >> (5 * c)) & 0x7FFF) << 30);
                unsigned nb = 0;
                #pragma unroll
                for (int b = 0; b < NB; ++b)
                    nb |= ((V & cm[c][b]) == 0ull ? 1u : 0u) << b;
                volatile unsigned char* pa = act_s + pc + c;
                if ((unsigned char)nb != *pa) {
                    *pa = (unsigned char)nb;
                    rowflag[pcur][row + 1] = 1u;   // benign all-write-1 race
                    mych = true;
                }
            }
        }
        if (__syncthreads_count(mych ? 1 : 0) == 0) break;
        int t0 = pprev; pprev = pcur; pcur = pnext; pnext = t0;
    }

    // Writeback: zero scores of suppressed boxes (score stored by kernel 1)
    if (wk) {
        #pragma unroll
        for (int c = 0; c < 4; ++c) {
            unsigned bits = act_s[pc + c];
            int j0 = (cell0 + c) * NB;
            #pragma unroll
            for (int b = 0; b < NB; ++b)
                if (!((bits >> b) & 1u)) out[(j0 + b) * 5 + 4] = 0.0f;
        }
    }
}

extern "C" void kernel_launch(void* const* d_in, const int* in_sizes, int n_in,
                              void* d_out, int out_size, void* d_ws, size_t ws_size,
                              hipStream_t stream) {
    const float* x = (const float*)d_in[0];
    float* out = (float*)d_out;

    // ws layout: masks u64[NB][NCELL] (plane-major)
    unsigned long long* masks = (unsigned long long*)d_ws;      // 108160 B

    decode_adj_kernel<<<NTX * NTY, 192, 0, stream>>>(x, out, masks);
    nms_kernel<<<1, BLK, 0, stream>>>(masks, out);
}